// Round 2
// baseline (190.458 us; speedup 1.0000x reference)
//
#include <hip/hip_runtime.h>
#include <math.h>

#define NJ 14
#define NE 42          // floats per item per tensor
#define TPB 256

// Single-instruction HW approx ops (~1 ulp) — error budget allows it
// (absmax 7.8e-3 with exact ops vs 4.7e-2 threshold).
__device__ __forceinline__ float frcp(float x) { return __builtin_amdgcn_rcpf(x); }
__device__ __forceinline__ float frsq(float x) { return __builtin_amdgcn_rsqf(x); }
__device__ __forceinline__ float fsqr(float x) { return __builtin_amdgcn_sqrtf(x); }

// Branchless cyclic Jacobi rotation on symmetric A, accumulating V.
// apq==0 degenerates to a harmless (still orthogonal) rotation; tau overflow
// (apq ~ 1e-30) gives t=0 -> identity. Both safe.
template <int p, int q, int r>
__device__ __forceinline__ void jrot(float A[3][3], float V[3][3]) {
    float apq = A[p][q];
    float apq_s = apq + copysignf(1e-30f, apq);
    float tau = (A[q][q] - A[p][p]) * 0.5f * frcp(apq_s);
    float t = copysignf(frcp(fabsf(tau) + fsqr(1.0f + tau * tau)), tau);
    float c = frsq(1.0f + t * t);
    float s = t * c;
    float app = A[p][p], aqq = A[q][q];
    A[p][p] = app - t * apq;
    A[q][q] = aqq + t * apq;
    A[p][q] = 0.0f;
    A[q][p] = 0.0f;
    float arp = A[r][p], arq = A[r][q];
    A[r][p] = c * arp - s * arq;
    A[p][r] = A[r][p];
    A[r][q] = s * arp + c * arq;
    A[q][r] = A[r][q];
#pragma unroll
    for (int k = 0; k < 3; ++k) {
        float vkp = V[k][p], vkq = V[k][q];
        V[k][p] = c * vkp - s * vkq;
        V[k][q] = s * vkp + c * vkq;
    }
}

// No LDS: occupancy was LDS-capped at 7 waves/CU. Direct per-thread float2
// loads (168 B item stride, 8B aligned); every 64B line in the wave's
// footprint is fully consumed so HBM bytes are identical, and 16 waves/CU
// hides the divergent-access latency. launch_bounds(256,4) caps VGPR at 128.
__global__ __launch_bounds__(TPB, 4) void pampjpe_kernel(
    const float* __restrict__ pred, const float* __restrict__ gt,
    float* __restrict__ out, int n_items) {
    const int me = blockIdx.x * TPB + threadIdx.x;
    if (me >= n_items) return;

    const float2* p2 = (const float2*)pred + (size_t)me * (NE / 2);
    const float2* g2 = (const float2*)gt + (size_t)me * (NE / 2);

    // ---- pass A: moments (2 joints = 3 float2 per tensor per step) ----
    float Sp0 = 0.f, Sp1 = 0.f, Sp2 = 0.f;
    float Sg0 = 0.f, Sg1 = 0.f, Sg2 = 0.f;
    float pp = 0.f;
    float M[3][3] = {{0.f, 0.f, 0.f}, {0.f, 0.f, 0.f}, {0.f, 0.f, 0.f}};

#define ACC(px, py, pz, gx, gy, gz)                                   \
    {                                                                 \
        Sp0 += (px); Sp1 += (py); Sp2 += (pz);                        \
        Sg0 += (gx); Sg1 += (gy); Sg2 += (gz);                        \
        pp += (px) * (px) + (py) * (py) + (pz) * (pz);                \
        M[0][0] += (px) * (gx); M[0][1] += (px) * (gy); M[0][2] += (px) * (gz); \
        M[1][0] += (py) * (gx); M[1][1] += (py) * (gy); M[1][2] += (py) * (gz); \
        M[2][0] += (pz) * (gx); M[2][1] += (pz) * (gy); M[2][2] += (pz) * (gz); \
    }

#pragma unroll
    for (int h = 0; h < 7; ++h) {
        float2 pa = p2[3 * h + 0], pb = p2[3 * h + 1], pc = p2[3 * h + 2];
        float2 ga = g2[3 * h + 0], gb = g2[3 * h + 1], gc = g2[3 * h + 2];
        ACC(pa.x, pa.y, pb.x, ga.x, ga.y, gb.x);
        ACC(pb.y, pc.x, pc.y, gb.y, gc.x, gc.y);
    }
#undef ACC

    const float invJ = 1.0f / (float)NJ;
    float mp[3] = {Sp0 * invJ, Sp1 * invJ, Sp2 * invJ};
    float mg[3] = {Sg0 * invJ, Sg1 * invJ, Sg2 * invJ};

    float K[3][3];
#pragma unroll
    for (int i = 0; i < 3; ++i)
#pragma unroll
        for (int j = 0; j < 3; ++j)
            K[i][j] = M[i][j] - (float)NJ * mp[i] * mg[j];
    float var1 = pp - (float)NJ * (mp[0] * mp[0] + mp[1] * mp[1] + mp[2] * mp[2]);
    var1 = fmaxf(var1, 1e-30f);

    // ---- A = K^T K, Jacobi eigendecomposition (6 sweeps, branchless) ----
    float A[3][3];
#pragma unroll
    for (int i = 0; i < 3; ++i)
#pragma unroll
        for (int j = 0; j < 3; ++j)
            A[i][j] = K[0][i] * K[0][j] + K[1][i] * K[1][j] + K[2][i] * K[2][j];
    float V[3][3] = {{1.f, 0.f, 0.f}, {0.f, 1.f, 0.f}, {0.f, 0.f, 1.f}};
#pragma unroll
    for (int sweep = 0; sweep < 6; ++sweep) {
        jrot<0, 1, 2>(A, V);
        jrot<0, 2, 1>(A, V);
        jrot<1, 2, 0>(A, V);
    }
    float lam0 = A[0][0], lam1 = A[1][1], lam2 = A[2][2];

#define SWAPCOL(la, lb, a, b)                                     \
    {                                                             \
        float _t;                                                 \
        _t = la; la = lb; lb = _t;                                \
        _t = V[0][a]; V[0][a] = V[0][b]; V[0][b] = _t;            \
        _t = V[1][a]; V[1][a] = V[1][b]; V[1][b] = _t;            \
        _t = V[2][a]; V[2][a] = V[2][b]; V[2][b] = _t;            \
    }
    if (lam0 < lam1) SWAPCOL(lam0, lam1, 0, 1)
    if (lam0 < lam2) SWAPCOL(lam0, lam2, 0, 2)
    if (lam1 < lam2) SWAPCOL(lam1, lam2, 1, 2)
#undef SWAPCOL

    float v0[3] = {V[0][0], V[1][0], V[2][0]};
    float v1[3] = {V[0][1], V[1][1], V[2][1]};
    float v2[3] = {V[0][2], V[1][2], V[2][2]};

    // det(V) = +1
    float cxx = v0[1] * v1[2] - v0[2] * v1[1];
    float cxy = v0[2] * v1[0] - v0[0] * v1[2];
    float cxz = v0[0] * v1[1] - v0[1] * v1[0];
    float detv = cxx * v2[0] + cxy * v2[1] + cxz * v2[2];
    if (detv < 0.f) { v2[0] = -v2[0]; v2[1] = -v2[1]; v2[2] = -v2[2]; }

    // U via K*v + Gram-Schmidt; u3 = u1 x u2 -> det(U)=+1
    float w0[3], w1[3];
#pragma unroll
    for (int i = 0; i < 3; ++i) {
        w0[i] = K[i][0] * v0[0] + K[i][1] * v0[1] + K[i][2] * v0[2];
        w1[i] = K[i][0] * v1[0] + K[i][1] * v1[1] + K[i][2] * v1[2];
    }
    float inv0 = frsq(fmaxf(w0[0] * w0[0] + w0[1] * w0[1] + w0[2] * w0[2], 1e-30f));
    float u1[3] = {w0[0] * inv0, w0[1] * inv0, w0[2] * inv0};
    float d1 = u1[0] * w1[0] + u1[1] * w1[1] + u1[2] * w1[2];
    w1[0] -= d1 * u1[0]; w1[1] -= d1 * u1[1]; w1[2] -= d1 * u1[2];
    float inv1 = frsq(fmaxf(w1[0] * w1[0] + w1[1] * w1[1] + w1[2] * w1[2], 1e-30f));
    float u2[3] = {w1[0] * inv1, w1[1] * inv1, w1[2] * inv1};
    float u3[3] = {u1[1] * u2[2] - u1[2] * u2[1],
                   u1[2] * u2[0] - u1[0] * u2[2],
                   u1[0] * u2[1] - u1[1] * u2[0]};

    // R = V U^T
    float R[3][3];
#pragma unroll
    for (int i = 0; i < 3; ++i) {
        R[i][0] = v0[i] * u1[0] + v1[i] * u2[0] + v2[i] * u3[0];
        R[i][1] = v0[i] * u1[1] + v1[i] * u2[1] + v2[i] * u3[1];
        R[i][2] = v0[i] * u1[2] + v1[i] * u2[2] + v2[i] * u3[2];
    }
    float trRK = 0.f;
#pragma unroll
    for (int i = 0; i < 3; ++i)
#pragma unroll
        for (int j = 0; j < 3; ++j)
            trRK += R[i][j] * K[j][i];
    float scale = trRK * frcp(var1);

    // ---- pass B: reload (L2-resident) and accumulate loss ----
    float acc = 0.f;
#define LOSS(px, py, pz, gx, gy, gz)                                          \
    {                                                                         \
        float x0 = (px) - mp[0], x1 = (py) - mp[1], x2 = (pz) - mp[2];        \
        float y0 = (gx) - mg[0], y1 = (gy) - mg[1], y2 = (gz) - mg[2];        \
        float e0 = scale * (R[0][0] * x0 + R[0][1] * x1 + R[0][2] * x2) - y0; \
        float e1 = scale * (R[1][0] * x0 + R[1][1] * x1 + R[1][2] * x2) - y1; \
        float e2 = scale * (R[2][0] * x0 + R[2][1] * x1 + R[2][2] * x2) - y2; \
        acc += fsqr(e0 * e0 + e1 * e1 + e2 * e2);                             \
    }
#pragma unroll
    for (int h = 0; h < 7; ++h) {
        float2 pa = p2[3 * h + 0], pb = p2[3 * h + 1], pc = p2[3 * h + 2];
        float2 ga = g2[3 * h + 0], gb = g2[3 * h + 1], gc = g2[3 * h + 2];
        LOSS(pa.x, pa.y, pb.x, ga.x, ga.y, gb.x);
        LOSS(pb.y, pc.x, pc.y, gb.y, gc.x, gc.y);
    }
#undef LOSS

    out[me] = acc * invJ;
}

extern "C" void kernel_launch(void* const* d_in, const int* in_sizes, int n_in,
                              void* d_out, int out_size, void* d_ws, size_t ws_size,
                              hipStream_t stream) {
    const float* pred = (const float*)d_in[0];
    const float* gt = (const float*)d_in[1];
    float* out = (float*)d_out;
    int n_items = in_sizes[0] / NE;  // 262144
    int grid = (n_items + TPB - 1) / TPB;
    pampjpe_kernel<<<grid, TPB, 0, stream>>>(pred, gt, out, n_items);
}

// Round 3
// 141.424 us; speedup vs baseline: 1.3467x; 1.3467x over previous
//
#include <hip/hip_runtime.h>
#include <math.h>

#define NJ 14
#define NE 42          // floats per item per tensor
#define TPB 256
#define CHUNK 128      // items staged per LDS pass
#define CDW (CHUNK * NE)  // 5376 dwords = 21504 B

__device__ __forceinline__ float frcp(float x) { return __builtin_amdgcn_rcpf(x); }
__device__ __forceinline__ float frsq(float x) { return __builtin_amdgcn_rsqf(x); }
__device__ __forceinline__ float fsqr(float x) { return __builtin_amdgcn_sqrtf(x); }

// Branchless cyclic Jacobi rotation on symmetric A, accumulating V.
template <int p, int q, int r>
__device__ __forceinline__ void jrot(float A[3][3], float V[3][3]) {
    float apq = A[p][q];
    float apq_s = apq + copysignf(1e-30f, apq);
    float tau = (A[q][q] - A[p][p]) * 0.5f * frcp(apq_s);
    float t = copysignf(frcp(fabsf(tau) + fsqr(1.0f + tau * tau)), tau);
    float c = frsq(1.0f + t * t);
    float s = t * c;
    float app = A[p][p], aqq = A[q][q];
    A[p][p] = app - t * apq;
    A[q][q] = aqq + t * apq;
    A[p][q] = 0.0f;
    A[q][p] = 0.0f;
    float arp = A[r][p], arq = A[r][q];
    A[r][p] = c * arp - s * arq;
    A[p][r] = A[r][p];
    A[r][q] = s * arp + c * arq;
    A[q][r] = A[r][q];
#pragma unroll
    for (int k = 0; k < 3; ++k) {
        float vkp = V[k][p], vkq = V[k][q];
        V[k][p] = c * vkp - s * vkq;
        V[k][q] = s * vkp + c * vkq;
    }
}

// Single-pass design: coalesced dwordx4 global->LDS staging (linear copy,
// zero address math), b64 LDS->register readback, all 84 floats held in
// registers so global memory is read EXACTLY once (round 2 fetched 3.1x).
// LDS buffer is reused across 4 stage phases -> only 21.5 KB static.
__global__ __launch_bounds__(TPB, 4) void pampjpe_kernel(
    const float* __restrict__ pred, const float* __restrict__ gt,
    float* __restrict__ out, int n_items) {
    __shared__ float s[CDW];

    const int tid = threadIdx.x;
    const int half = tid >> 7;   // which 128-item chunk holds my item
    const int li = tid & 127;    // my index within that chunk
    const long long blk_base = (long long)blockIdx.x * TPB * NE;
    const long long lim4 = (long long)n_items * NE - 4;
    const long long lim1 = (long long)n_items * NE - 1;

    float pd[NE], gd[NE];

#pragma unroll
    for (int t = 0; t < 2; ++t) {
        const float* __restrict__ src = (t == 0) ? pred : gt;
        float* dst = (t == 0) ? pd : gd;
#pragma unroll
        for (int c = 0; c < 2; ++c) {
            const long long cbase = blk_base + (long long)c * CDW;
            // stage: 5 x dwordx4 + 1 x dword per thread, fully coalesced
#pragma unroll
            for (int k = 0; k < 5; ++k) {
                int idx = (k * TPB + tid) * 4;
                long long g = cbase + idx;
                g = g > lim4 ? lim4 : g;  // tail safety (never hit: 262144%256==0)
                float4 v = *(const float4*)(src + g);
                *(float4*)(s + idx) = v;
            }
            {
                int idx = 5 * TPB * 4 + tid;  // 5120..5375
                long long g = cbase + idx;
                g = g > lim1 ? lim1 : g;
                s[idx] = src[g];
            }
            __syncthreads();
            if (half == c) {
#pragma unroll
                for (int e = 0; e < NE; e += 2) {
                    float2 v = *(const float2*)(s + li * NE + e);  // 8B-aligned: 42*li even
                    dst[e] = v.x;
                    dst[e + 1] = v.y;
                }
            }
            __syncthreads();
        }
    }

    const int me = blockIdx.x * TPB + tid;

    // ---- moments ----
    float Sp0 = 0.f, Sp1 = 0.f, Sp2 = 0.f;
    float Sg0 = 0.f, Sg1 = 0.f, Sg2 = 0.f;
    float pp = 0.f;
    float M[3][3] = {{0.f, 0.f, 0.f}, {0.f, 0.f, 0.f}, {0.f, 0.f, 0.f}};
#pragma unroll
    for (int j = 0; j < NJ; ++j) {
        float px = pd[3 * j + 0], py = pd[3 * j + 1], pz = pd[3 * j + 2];
        float gx = gd[3 * j + 0], gy = gd[3 * j + 1], gz = gd[3 * j + 2];
        Sp0 += px; Sp1 += py; Sp2 += pz;
        Sg0 += gx; Sg1 += gy; Sg2 += gz;
        pp += px * px + py * py + pz * pz;
        M[0][0] += px * gx; M[0][1] += px * gy; M[0][2] += px * gz;
        M[1][0] += py * gx; M[1][1] += py * gy; M[1][2] += py * gz;
        M[2][0] += pz * gx; M[2][1] += pz * gy; M[2][2] += pz * gz;
    }
    const float invJ = 1.0f / (float)NJ;
    float mp[3] = {Sp0 * invJ, Sp1 * invJ, Sp2 * invJ};
    float mg[3] = {Sg0 * invJ, Sg1 * invJ, Sg2 * invJ};

    float K[3][3];
#pragma unroll
    for (int i = 0; i < 3; ++i)
#pragma unroll
        for (int j = 0; j < 3; ++j)
            K[i][j] = M[i][j] - (float)NJ * mp[i] * mg[j];
    float var1 = pp - (float)NJ * (mp[0] * mp[0] + mp[1] * mp[1] + mp[2] * mp[2]);
    var1 = fmaxf(var1, 1e-30f);

    // ---- A = K^T K, Jacobi (5 sweeps, branchless) ----
    float A[3][3];
#pragma unroll
    for (int i = 0; i < 3; ++i)
#pragma unroll
        for (int j = 0; j < 3; ++j)
            A[i][j] = K[0][i] * K[0][j] + K[1][i] * K[1][j] + K[2][i] * K[2][j];
    float V[3][3] = {{1.f, 0.f, 0.f}, {0.f, 1.f, 0.f}, {0.f, 0.f, 1.f}};
#pragma unroll
    for (int sweep = 0; sweep < 5; ++sweep) {
        jrot<0, 1, 2>(A, V);
        jrot<0, 2, 1>(A, V);
        jrot<1, 2, 0>(A, V);
    }
    float lam0 = A[0][0], lam1 = A[1][1], lam2 = A[2][2];

#define SWAPCOL(la, lb, a, b)                                     \
    {                                                             \
        float _t;                                                 \
        _t = la; la = lb; lb = _t;                                \
        _t = V[0][a]; V[0][a] = V[0][b]; V[0][b] = _t;            \
        _t = V[1][a]; V[1][a] = V[1][b]; V[1][b] = _t;            \
        _t = V[2][a]; V[2][a] = V[2][b]; V[2][b] = _t;            \
    }
    if (lam0 < lam1) SWAPCOL(lam0, lam1, 0, 1)
    if (lam0 < lam2) SWAPCOL(lam0, lam2, 0, 2)
    if (lam1 < lam2) SWAPCOL(lam1, lam2, 1, 2)
#undef SWAPCOL

    float v0[3] = {V[0][0], V[1][0], V[2][0]};
    float v1[3] = {V[0][1], V[1][1], V[2][1]};
    float v2[3] = {V[0][2], V[1][2], V[2][2]};

    // det(V) = +1
    float cxx = v0[1] * v1[2] - v0[2] * v1[1];
    float cxy = v0[2] * v1[0] - v0[0] * v1[2];
    float cxz = v0[0] * v1[1] - v0[1] * v1[0];
    float detv = cxx * v2[0] + cxy * v2[1] + cxz * v2[2];
    if (detv < 0.f) { v2[0] = -v2[0]; v2[1] = -v2[1]; v2[2] = -v2[2]; }

    // U via K*v + Gram-Schmidt; u3 = u1 x u2 -> det(U)=+1
    float w0[3], w1[3];
#pragma unroll
    for (int i = 0; i < 3; ++i) {
        w0[i] = K[i][0] * v0[0] + K[i][1] * v0[1] + K[i][2] * v0[2];
        w1[i] = K[i][0] * v1[0] + K[i][1] * v1[1] + K[i][2] * v1[2];
    }
    float inv0 = frsq(fmaxf(w0[0] * w0[0] + w0[1] * w0[1] + w0[2] * w0[2], 1e-30f));
    float u1[3] = {w0[0] * inv0, w0[1] * inv0, w0[2] * inv0};
    float d1 = u1[0] * w1[0] + u1[1] * w1[1] + u1[2] * w1[2];
    w1[0] -= d1 * u1[0]; w1[1] -= d1 * u1[1]; w1[2] -= d1 * u1[2];
    float inv1 = frsq(fmaxf(w1[0] * w1[0] + w1[1] * w1[1] + w1[2] * w1[2], 1e-30f));
    float u2[3] = {w1[0] * inv1, w1[1] * inv1, w1[2] * inv1};
    float u3[3] = {u1[1] * u2[2] - u1[2] * u2[1],
                   u1[2] * u2[0] - u1[0] * u2[2],
                   u1[0] * u2[1] - u1[1] * u2[0]};

    // R = V U^T
    float R[3][3];
#pragma unroll
    for (int i = 0; i < 3; ++i) {
        R[i][0] = v0[i] * u1[0] + v1[i] * u2[0] + v2[i] * u3[0];
        R[i][1] = v0[i] * u1[1] + v1[i] * u2[1] + v2[i] * u3[1];
        R[i][2] = v0[i] * u1[2] + v1[i] * u2[2] + v2[i] * u3[2];
    }
    float trRK = 0.f;
#pragma unroll
    for (int i = 0; i < 3; ++i)
#pragma unroll
        for (int j = 0; j < 3; ++j)
            trRK += R[i][j] * K[j][i];
    float scale = trRK * frcp(var1);

    // ---- loss from registers (no reload) ----
    float acc = 0.f;
#pragma unroll
    for (int j = 0; j < NJ; ++j) {
        float x0 = pd[3 * j + 0] - mp[0];
        float x1 = pd[3 * j + 1] - mp[1];
        float x2 = pd[3 * j + 2] - mp[2];
        float y0 = gd[3 * j + 0] - mg[0];
        float y1 = gd[3 * j + 1] - mg[1];
        float y2 = gd[3 * j + 2] - mg[2];
        float e0 = scale * (R[0][0] * x0 + R[0][1] * x1 + R[0][2] * x2) - y0;
        float e1 = scale * (R[1][0] * x0 + R[1][1] * x1 + R[1][2] * x2) - y1;
        float e2 = scale * (R[2][0] * x0 + R[2][1] * x1 + R[2][2] * x2) - y2;
        acc += fsqr(e0 * e0 + e1 * e1 + e2 * e2);
    }
    if (me < n_items) out[me] = acc * invJ;
}

extern "C" void kernel_launch(void* const* d_in, const int* in_sizes, int n_in,
                              void* d_out, int out_size, void* d_ws, size_t ws_size,
                              hipStream_t stream) {
    const float* pred = (const float*)d_in[0];
    const float* gt = (const float*)d_in[1];
    float* out = (float*)d_out;
    int n_items = in_sizes[0] / NE;  // 262144
    int grid = (n_items + TPB - 1) / TPB;
    pampjpe_kernel<<<grid, TPB, 0, stream>>>(pred, gt, out, n_items);
}

// Round 4
// 140.080 us; speedup vs baseline: 1.3596x; 1.0096x over previous
//
#include <hip/hip_runtime.h>
#include <math.h>

#define NJ 14
#define NE 42            // floats per item per tensor
#define TPB 256
#define CHUNK 128        // items staged per LDS phase
#define CDW (CHUNK * NE) // 5376 dwords = 21504 B

__device__ __forceinline__ float frcp(float x) { return __builtin_amdgcn_rcpf(x); }
__device__ __forceinline__ float frsq(float x) { return __builtin_amdgcn_rsqf(x); }
__device__ __forceinline__ float fsqr(float x) { return __builtin_amdgcn_sqrtf(x); }

// Branchless cyclic Jacobi rotation on symmetric A, accumulating V.
template <int p, int q, int r>
__device__ __forceinline__ void jrot(float A[3][3], float V[3][3]) {
    float apq = A[p][q];
    float apq_s = apq + copysignf(1e-30f, apq);
    float tau = (A[q][q] - A[p][p]) * 0.5f * frcp(apq_s);
    float t = copysignf(frcp(fabsf(tau) + fsqr(1.0f + tau * tau)), tau);
    float c = frsq(1.0f + t * t);
    float s = t * c;
    float app = A[p][p], aqq = A[q][q];
    A[p][p] = app - t * apq;
    A[q][q] = aqq + t * apq;
    A[p][q] = 0.0f;
    A[q][p] = 0.0f;
    float arp = A[r][p], arq = A[r][q];
    A[r][p] = c * arp - s * arq;
    A[p][r] = A[r][p];
    A[r][q] = s * arp + c * arq;
    A[q][r] = A[r][q];
#pragma unroll
    for (int k = 0; k < 3; ++k) {
        float vkp = V[k][p], vkq = V[k][q];
        V[k][p] = c * vkp - s * vkq;
        V[k][q] = s * vkp + c * vkq;
    }
}

// Round-3 bug: `dst = (t==0) ? pd : gd` runtime pointer made the local
// arrays address-taken -> SROA failed -> 84 floats/thread spilled to
// scratch (WRITE_SIZE 70 MB, VGPR_Count 64). Fix: macros that name the
// destination array directly; all indices compile-time constants.
#define STAGE(SRC, CBASE)                                                  \
    {                                                                      \
        _Pragma("unroll") for (int k = 0; k < 5; ++k) {                    \
            int idx = (k * TPB + tid) * 4;                                 \
            long long g = (CBASE) + idx;                                   \
            g = g > lim4 ? lim4 : g;                                       \
            *(float4*)(s + idx) = *(const float4*)((SRC) + g);             \
        }                                                                  \
        {                                                                  \
            int idx = 5 * TPB * 4 + tid;                                   \
            long long g = (CBASE) + idx;                                   \
            g = g > lim1 ? lim1 : g;                                       \
            s[idx] = (SRC)[g];                                             \
        }                                                                  \
    }

#define READBACK(DST)                                                      \
    {                                                                      \
        _Pragma("unroll") for (int e = 0; e < NE; e += 2) {                \
            float2 v = *(const float2*)(s + li * NE + e);                  \
            (DST)[e] = v.x;                                                \
            (DST)[e + 1] = v.y;                                            \
        }                                                                  \
    }

__global__ __launch_bounds__(TPB, 4) void pampjpe_kernel(
    const float* __restrict__ pred, const float* __restrict__ gt,
    float* __restrict__ out, int n_items) {
    __shared__ float s[CDW];

    const int tid = threadIdx.x;
    const int half = tid >> 7;   // which 128-item chunk holds my item
    const int li = tid & 127;    // my index within that chunk
    const long long blk_base = (long long)blockIdx.x * TPB * NE;
    const long long lim4 = (long long)n_items * NE - 4;
    const long long lim1 = (long long)n_items * NE - 1;

    float pd[NE], gd[NE];

    // ---- stage pred: chunk 0 then chunk 1 ----
    STAGE(pred, blk_base);
    __syncthreads();
    if (half == 0) READBACK(pd);
    __syncthreads();
    STAGE(pred, blk_base + CDW);
    __syncthreads();
    if (half == 1) READBACK(pd);
    __syncthreads();
    // ---- stage gt ----
    STAGE(gt, blk_base);
    __syncthreads();
    if (half == 0) READBACK(gd);
    __syncthreads();
    STAGE(gt, blk_base + CDW);
    __syncthreads();
    if (half == 1) READBACK(gd);
    // no trailing barrier needed: LDS not touched again

    const int me = blockIdx.x * TPB + tid;

    // ---- moments ----
    float Sp0 = 0.f, Sp1 = 0.f, Sp2 = 0.f;
    float Sg0 = 0.f, Sg1 = 0.f, Sg2 = 0.f;
    float pp = 0.f;
    float M[3][3] = {{0.f, 0.f, 0.f}, {0.f, 0.f, 0.f}, {0.f, 0.f, 0.f}};
#pragma unroll
    for (int j = 0; j < NJ; ++j) {
        float px = pd[3 * j + 0], py = pd[3 * j + 1], pz = pd[3 * j + 2];
        float gx = gd[3 * j + 0], gy = gd[3 * j + 1], gz = gd[3 * j + 2];
        Sp0 += px; Sp1 += py; Sp2 += pz;
        Sg0 += gx; Sg1 += gy; Sg2 += gz;
        pp += px * px + py * py + pz * pz;
        M[0][0] += px * gx; M[0][1] += px * gy; M[0][2] += px * gz;
        M[1][0] += py * gx; M[1][1] += py * gy; M[1][2] += py * gz;
        M[2][0] += pz * gx; M[2][1] += pz * gy; M[2][2] += pz * gz;
    }
    const float invJ = 1.0f / (float)NJ;
    float mp[3] = {Sp0 * invJ, Sp1 * invJ, Sp2 * invJ};
    float mg[3] = {Sg0 * invJ, Sg1 * invJ, Sg2 * invJ};

    float K[3][3];
#pragma unroll
    for (int i = 0; i < 3; ++i)
#pragma unroll
        for (int j = 0; j < 3; ++j)
            K[i][j] = M[i][j] - (float)NJ * mp[i] * mg[j];
    float var1 = pp - (float)NJ * (mp[0] * mp[0] + mp[1] * mp[1] + mp[2] * mp[2]);
    var1 = fmaxf(var1, 1e-30f);

    // ---- A = K^T K, Jacobi (5 sweeps, branchless) ----
    float A[3][3];
#pragma unroll
    for (int i = 0; i < 3; ++i)
#pragma unroll
        for (int j = 0; j < 3; ++j)
            A[i][j] = K[0][i] * K[0][j] + K[1][i] * K[1][j] + K[2][i] * K[2][j];
    float V[3][3] = {{1.f, 0.f, 0.f}, {0.f, 1.f, 0.f}, {0.f, 0.f, 1.f}};
#pragma unroll
    for (int sweep = 0; sweep < 5; ++sweep) {
        jrot<0, 1, 2>(A, V);
        jrot<0, 2, 1>(A, V);
        jrot<1, 2, 0>(A, V);
    }
    float lam0 = A[0][0], lam1 = A[1][1], lam2 = A[2][2];

#define SWAPCOL(la, lb, a, b)                                     \
    {                                                             \
        float _t;                                                 \
        _t = la; la = lb; lb = _t;                                \
        _t = V[0][a]; V[0][a] = V[0][b]; V[0][b] = _t;            \
        _t = V[1][a]; V[1][a] = V[1][b]; V[1][b] = _t;            \
        _t = V[2][a]; V[2][a] = V[2][b]; V[2][b] = _t;            \
    }
    if (lam0 < lam1) SWAPCOL(lam0, lam1, 0, 1)
    if (lam0 < lam2) SWAPCOL(lam0, lam2, 0, 2)
    if (lam1 < lam2) SWAPCOL(lam1, lam2, 1, 2)
#undef SWAPCOL

    float v0[3] = {V[0][0], V[1][0], V[2][0]};
    float v1[3] = {V[0][1], V[1][1], V[2][1]};
    float v2[3] = {V[0][2], V[1][2], V[2][2]};

    // det(V) = +1
    float cxx = v0[1] * v1[2] - v0[2] * v1[1];
    float cxy = v0[2] * v1[0] - v0[0] * v1[2];
    float cxz = v0[0] * v1[1] - v0[1] * v1[0];
    float detv = cxx * v2[0] + cxy * v2[1] + cxz * v2[2];
    if (detv < 0.f) { v2[0] = -v2[0]; v2[1] = -v2[1]; v2[2] = -v2[2]; }

    // U via K*v + Gram-Schmidt; u3 = u1 x u2 -> det(U)=+1
    float w0[3], w1[3];
#pragma unroll
    for (int i = 0; i < 3; ++i) {
        w0[i] = K[i][0] * v0[0] + K[i][1] * v0[1] + K[i][2] * v0[2];
        w1[i] = K[i][0] * v1[0] + K[i][1] * v1[1] + K[i][2] * v1[2];
    }
    float inv0 = frsq(fmaxf(w0[0] * w0[0] + w0[1] * w0[1] + w0[2] * w0[2], 1e-30f));
    float u1[3] = {w0[0] * inv0, w0[1] * inv0, w0[2] * inv0};
    float d1 = u1[0] * w1[0] + u1[1] * w1[1] + u1[2] * w1[2];
    w1[0] -= d1 * u1[0]; w1[1] -= d1 * u1[1]; w1[2] -= d1 * u1[2];
    float inv1 = frsq(fmaxf(w1[0] * w1[0] + w1[1] * w1[1] + w1[2] * w1[2], 1e-30f));
    float u2[3] = {w1[0] * inv1, w1[1] * inv1, w1[2] * inv1};
    float u3[3] = {u1[1] * u2[2] - u1[2] * u2[1],
                   u1[2] * u2[0] - u1[0] * u2[2],
                   u1[0] * u2[1] - u1[1] * u2[0]};

    // R = V U^T
    float R[3][3];
#pragma unroll
    for (int i = 0; i < 3; ++i) {
        R[i][0] = v0[i] * u1[0] + v1[i] * u2[0] + v2[i] * u3[0];
        R[i][1] = v0[i] * u1[1] + v1[i] * u2[1] + v2[i] * u3[1];
        R[i][2] = v0[i] * u1[2] + v1[i] * u2[2] + v2[i] * u3[2];
    }
    float trRK = 0.f;
#pragma unroll
    for (int i = 0; i < 3; ++i)
#pragma unroll
        for (int j = 0; j < 3; ++j)
            trRK += R[i][j] * K[j][i];
    float scale = trRK * frcp(var1);

    // ---- loss from registers (no reload) ----
    float acc = 0.f;
#pragma unroll
    for (int j = 0; j < NJ; ++j) {
        float x0 = pd[3 * j + 0] - mp[0];
        float x1 = pd[3 * j + 1] - mp[1];
        float x2 = pd[3 * j + 2] - mp[2];
        float y0 = gd[3 * j + 0] - mg[0];
        float y1 = gd[3 * j + 1] - mg[1];
        float y2 = gd[3 * j + 2] - mg[2];
        float e0 = scale * (R[0][0] * x0 + R[0][1] * x1 + R[0][2] * x2) - y0;
        float e1 = scale * (R[1][0] * x0 + R[1][1] * x1 + R[1][2] * x2) - y1;
        float e2 = scale * (R[2][0] * x0 + R[2][1] * x1 + R[2][2] * x2) - y2;
        acc += fsqr(e0 * e0 + e1 * e1 + e2 * e2);
    }
    if (me < n_items) out[me] = acc * invJ;
}

extern "C" void kernel_launch(void* const* d_in, const int* in_sizes, int n_in,
                              void* d_out, int out_size, void* d_ws, size_t ws_size,
                              hipStream_t stream) {
    const float* pred = (const float*)d_in[0];
    const float* gt = (const float*)d_in[1];
    float* out = (float*)d_out;
    int n_items = in_sizes[0] / NE;  // 262144
    int grid = (n_items + TPB - 1) / TPB;
    pampjpe_kernel<<<grid, TPB, 0, stream>>>(pred, gt, out, n_items);
}

// Round 5
// 113.246 us; speedup vs baseline: 1.6818x; 1.2370x over previous
//
#include <hip/hip_runtime.h>
#include <math.h>

#define NJ 14
#define NE 42            // floats per item per tensor
#define TPB 256
#define CHUNK 128        // items staged per LDS phase
#define CDW (CHUNK * NE) // 5376 dwords = 21504 B

__device__ __forceinline__ float frcp(float x) { return __builtin_amdgcn_rcpf(x); }
__device__ __forceinline__ float frsq(float x) { return __builtin_amdgcn_rsqf(x); }
__device__ __forceinline__ float fsqr(float x) { return __builtin_amdgcn_sqrtf(x); }

// Branchless cyclic Jacobi rotation on symmetric A, accumulating V.
template <int p, int q, int r>
__device__ __forceinline__ void jrot(float A[3][3], float V[3][3]) {
    float apq = A[p][q];
    float apq_s = apq + copysignf(1e-30f, apq);
    float tau = (A[q][q] - A[p][p]) * 0.5f * frcp(apq_s);
    float t = copysignf(frcp(fabsf(tau) + fsqr(1.0f + tau * tau)), tau);
    float c = frsq(1.0f + t * t);
    float s = t * c;
    float app = A[p][p], aqq = A[q][q];
    A[p][p] = app - t * apq;
    A[q][q] = aqq + t * apq;
    A[p][q] = 0.0f;
    A[q][p] = 0.0f;
    float arp = A[r][p], arq = A[r][q];
    A[r][p] = c * arp - s * arq;
    A[p][r] = A[r][p];
    A[r][q] = s * arp + c * arq;
    A[q][r] = A[r][q];
#pragma unroll
    for (int k = 0; k < 3; ++k) {
        float vkp = V[k][p], vkq = V[k][q];
        V[k][p] = c * vkp - s * vkq;
        V[k][q] = s * vkp + c * vkq;
    }
}

#define STAGE(SRC, CBASE)                                                  \
    {                                                                      \
        _Pragma("unroll") for (int k = 0; k < 5; ++k) {                    \
            int idx = (k * TPB + tid) * 4;                                 \
            long long g = (CBASE) + idx;                                   \
            g = g > lim4 ? lim4 : g;                                       \
            *(float4*)(s + idx) = *(const float4*)((SRC) + g);             \
        }                                                                  \
        {                                                                  \
            int idx = 5 * TPB * 4 + tid;                                   \
            long long g = (CBASE) + idx;                                   \
            g = g > lim1 ? lim1 : g;                                       \
            s[idx] = (SRC)[g];                                             \
        }                                                                  \
    }

#define READBACK(DST)                                                      \
    {                                                                      \
        _Pragma("unroll") for (int e = 0; e < NE; e += 2) {                \
            float2 v = *(const float2*)(s + li * NE + e);                  \
            (DST)[e] = v.x;                                                \
            (DST)[e + 1] = v.y;                                            \
        }                                                                  \
    }

// KEY FIX vs rounds 2-4: __launch_bounds__(256, 4) — the min-waves/EU=4
// argument — capped the allocator at 64 arch VGPRs, spilling ~60 floats/
// thread to scratch (WRITE_SIZE 66 MB, VGPR_Count pinned at 64 across 3
// rounds; round 1 without the arg allocated 88 VGPRs, WRITE 1 MB). Drop
// the second arg and let the allocator hold the 84 data floats + Jacobi
// working set (~150 VGPRs, ~12 waves/CU) with ZERO scratch.
__global__ __launch_bounds__(TPB) void pampjpe_kernel(
    const float* __restrict__ pred, const float* __restrict__ gt,
    float* __restrict__ out, int n_items) {
    __shared__ float s[CDW];

    const int tid = threadIdx.x;
    const int half = tid >> 7;   // which 128-item chunk holds my item
    const int li = tid & 127;    // my index within that chunk
    const long long blk_base = (long long)blockIdx.x * TPB * NE;
    const long long lim4 = (long long)n_items * NE - 4;
    const long long lim1 = (long long)n_items * NE - 1;

    float pd[NE], gd[NE];

    // ---- stage pred: chunk 0 then chunk 1 ----
    STAGE(pred, blk_base);
    __syncthreads();
    if (half == 0) READBACK(pd);
    __syncthreads();
    STAGE(pred, blk_base + CDW);
    __syncthreads();
    if (half == 1) READBACK(pd);
    __syncthreads();
    // ---- stage gt ----
    STAGE(gt, blk_base);
    __syncthreads();
    if (half == 0) READBACK(gd);
    __syncthreads();
    STAGE(gt, blk_base + CDW);
    __syncthreads();
    if (half == 1) READBACK(gd);
    // no trailing barrier needed: LDS not touched again

    const int me = blockIdx.x * TPB + tid;

    // ---- moments ----
    float Sp0 = 0.f, Sp1 = 0.f, Sp2 = 0.f;
    float Sg0 = 0.f, Sg1 = 0.f, Sg2 = 0.f;
    float pp = 0.f;
    float M[3][3] = {{0.f, 0.f, 0.f}, {0.f, 0.f, 0.f}, {0.f, 0.f, 0.f}};
#pragma unroll
    for (int j = 0; j < NJ; ++j) {
        float px = pd[3 * j + 0], py = pd[3 * j + 1], pz = pd[3 * j + 2];
        float gx = gd[3 * j + 0], gy = gd[3 * j + 1], gz = gd[3 * j + 2];
        Sp0 += px; Sp1 += py; Sp2 += pz;
        Sg0 += gx; Sg1 += gy; Sg2 += gz;
        pp += px * px + py * py + pz * pz;
        M[0][0] += px * gx; M[0][1] += px * gy; M[0][2] += px * gz;
        M[1][0] += py * gx; M[1][1] += py * gy; M[1][2] += py * gz;
        M[2][0] += pz * gx; M[2][1] += pz * gy; M[2][2] += pz * gz;
    }
    const float invJ = 1.0f / (float)NJ;
    float mp[3] = {Sp0 * invJ, Sp1 * invJ, Sp2 * invJ};
    float mg[3] = {Sg0 * invJ, Sg1 * invJ, Sg2 * invJ};

    float K[3][3];
#pragma unroll
    for (int i = 0; i < 3; ++i)
#pragma unroll
        for (int j = 0; j < 3; ++j)
            K[i][j] = M[i][j] - (float)NJ * mp[i] * mg[j];
    float var1 = pp - (float)NJ * (mp[0] * mp[0] + mp[1] * mp[1] + mp[2] * mp[2]);
    var1 = fmaxf(var1, 1e-30f);

    // ---- A = K^T K, Jacobi (5 sweeps, branchless) ----
    float A[3][3];
#pragma unroll
    for (int i = 0; i < 3; ++i)
#pragma unroll
        for (int j = 0; j < 3; ++j)
            A[i][j] = K[0][i] * K[0][j] + K[1][i] * K[1][j] + K[2][i] * K[2][j];
    float V[3][3] = {{1.f, 0.f, 0.f}, {0.f, 1.f, 0.f}, {0.f, 0.f, 1.f}};
#pragma unroll
    for (int sweep = 0; sweep < 5; ++sweep) {
        jrot<0, 1, 2>(A, V);
        jrot<0, 2, 1>(A, V);
        jrot<1, 2, 0>(A, V);
    }
    float lam0 = A[0][0], lam1 = A[1][1], lam2 = A[2][2];

#define SWAPCOL(la, lb, a, b)                                     \
    {                                                             \
        float _t;                                                 \
        _t = la; la = lb; lb = _t;                                \
        _t = V[0][a]; V[0][a] = V[0][b]; V[0][b] = _t;            \
        _t = V[1][a]; V[1][a] = V[1][b]; V[1][b] = _t;            \
        _t = V[2][a]; V[2][a] = V[2][b]; V[2][b] = _t;            \
    }
    if (lam0 < lam1) SWAPCOL(lam0, lam1, 0, 1)
    if (lam0 < lam2) SWAPCOL(lam0, lam2, 0, 2)
    if (lam1 < lam2) SWAPCOL(lam1, lam2, 1, 2)
#undef SWAPCOL

    float v0[3] = {V[0][0], V[1][0], V[2][0]};
    float v1[3] = {V[0][1], V[1][1], V[2][1]};
    float v2[3] = {V[0][2], V[1][2], V[2][2]};

    // det(V) = +1
    float cxx = v0[1] * v1[2] - v0[2] * v1[1];
    float cxy = v0[2] * v1[0] - v0[0] * v1[2];
    float cxz = v0[0] * v1[1] - v0[1] * v1[0];
    float detv = cxx * v2[0] + cxy * v2[1] + cxz * v2[2];
    if (detv < 0.f) { v2[0] = -v2[0]; v2[1] = -v2[1]; v2[2] = -v2[2]; }

    // U via K*v + Gram-Schmidt; u3 = u1 x u2 -> det(U)=+1
    float w0[3], w1[3];
#pragma unroll
    for (int i = 0; i < 3; ++i) {
        w0[i] = K[i][0] * v0[0] + K[i][1] * v0[1] + K[i][2] * v0[2];
        w1[i] = K[i][0] * v1[0] + K[i][1] * v1[1] + K[i][2] * v1[2];
    }
    float inv0 = frsq(fmaxf(w0[0] * w0[0] + w0[1] * w0[1] + w0[2] * w0[2], 1e-30f));
    float u1[3] = {w0[0] * inv0, w0[1] * inv0, w0[2] * inv0};
    float d1 = u1[0] * w1[0] + u1[1] * w1[1] + u1[2] * w1[2];
    w1[0] -= d1 * u1[0]; w1[1] -= d1 * u1[1]; w1[2] -= d1 * u1[2];
    float inv1 = frsq(fmaxf(w1[0] * w1[0] + w1[1] * w1[1] + w1[2] * w1[2], 1e-30f));
    float u2[3] = {w1[0] * inv1, w1[1] * inv1, w1[2] * inv1};
    float u3[3] = {u1[1] * u2[2] - u1[2] * u2[1],
                   u1[2] * u2[0] - u1[0] * u2[2],
                   u1[0] * u2[1] - u1[1] * u2[0]};

    // R = V U^T
    float R[3][3];
#pragma unroll
    for (int i = 0; i < 3; ++i) {
        R[i][0] = v0[i] * u1[0] + v1[i] * u2[0] + v2[i] * u3[0];
        R[i][1] = v0[i] * u1[1] + v1[i] * u2[1] + v2[i] * u3[1];
        R[i][2] = v0[i] * u1[2] + v1[i] * u2[2] + v2[i] * u3[2];
    }
    float trRK = 0.f;
#pragma unroll
    for (int i = 0; i < 3; ++i)
#pragma unroll
        for (int j = 0; j < 3; ++j)
            trRK += R[i][j] * K[j][i];
    float scale = trRK * frcp(var1);

    // ---- loss from registers (no reload) ----
    float acc = 0.f;
#pragma unroll
    for (int j = 0; j < NJ; ++j) {
        float x0 = pd[3 * j + 0] - mp[0];
        float x1 = pd[3 * j + 1] - mp[1];
        float x2 = pd[3 * j + 2] - mp[2];
        float y0 = gd[3 * j + 0] - mg[0];
        float y1 = gd[3 * j + 1] - mg[1];
        float y2 = gd[3 * j + 2] - mg[2];
        float e0 = scale * (R[0][0] * x0 + R[0][1] * x1 + R[0][2] * x2) - y0;
        float e1 = scale * (R[1][0] * x0 + R[1][1] * x1 + R[1][2] * x2) - y1;
        float e2 = scale * (R[2][0] * x0 + R[2][1] * x1 + R[2][2] * x2) - y2;
        acc += fsqr(e0 * e0 + e1 * e1 + e2 * e2);
    }
    if (me < n_items) out[me] = acc * invJ;
}

extern "C" void kernel_launch(void* const* d_in, const int* in_sizes, int n_in,
                              void* d_out, int out_size, void* d_ws, size_t ws_size,
                              hipStream_t stream) {
    const float* pred = (const float*)d_in[0];
    const float* gt = (const float*)d_in[1];
    float* out = (float*)d_out;
    int n_items = in_sizes[0] / NE;  // 262144
    int grid = (n_items + TPB - 1) / TPB;
    pampjpe_kernel<<<grid, TPB, 0, stream>>>(pred, gt, out, n_items);
}

// Round 6
// 108.765 us; speedup vs baseline: 1.7511x; 1.0412x over previous
//
#include <hip/hip_runtime.h>
#include <math.h>

#define NJ 14
#define NE 42            // floats per item per tensor
#define TPB 64           // ONE wave per block -> wave-synchronous LDS, zero barriers
#define SLICE (TPB * NE) // 2688 dwords = 10752 B per tensor

__device__ __forceinline__ float frcp(float x) { return __builtin_amdgcn_rcpf(x); }
__device__ __forceinline__ float frsq(float x) { return __builtin_amdgcn_rsqf(x); }
__device__ __forceinline__ float fsqr(float x) { return __builtin_amdgcn_sqrtf(x); }

// Branchless cyclic Jacobi rotation on symmetric A, accumulating V.
template <int p, int q, int r>
__device__ __forceinline__ void jrot(float A[3][3], float V[3][3]) {
    float apq = A[p][q];
    float apq_s = apq + copysignf(1e-30f, apq);
    float tau = (A[q][q] - A[p][p]) * 0.5f * frcp(apq_s);
    float t = copysignf(frcp(fabsf(tau) + fsqr(1.0f + tau * tau)), tau);
    float c = frsq(1.0f + t * t);
    float s = t * c;
    float app = A[p][p], aqq = A[q][q];
    A[p][p] = app - t * apq;
    A[q][q] = aqq + t * apq;
    A[p][q] = 0.0f;
    A[q][p] = 0.0f;
    float arp = A[r][p], arq = A[r][q];
    A[r][p] = c * arp - s * arq;
    A[p][r] = A[r][p];
    A[r][q] = s * arp + c * arq;
    A[q][r] = A[r][q];
#pragma unroll
    for (int k = 0; k < 3; ++k) {
        float vkp = V[k][p], vkq = V[k][q];
        V[k][p] = c * vkp - s * vkq;
        V[k][q] = s * vkp + c * vkq;
    }
}

// Round-5 was latency-bound: 8 __syncthreads phases, each a full vmcnt(0)
// drain with no cross-phase overlap (HBM ~12%, VALU ~19%, dur 46us vs ~7us
// BW floor). Fix: 1-wave blocks + private LDS slices. Same wave writes and
// reads its LDS (DS pipe is in-order per wave) -> ZERO barriers; all 22
// staging loads are in flight at once; 4096 blocks pipeline across CUs.
__global__ __launch_bounds__(TPB) void pampjpe_kernel(
    const float* __restrict__ pred, const float* __restrict__ gt,
    float* __restrict__ out, int n_items) {
    __shared__ float sp[SLICE];
    __shared__ float sg[SLICE];

    const int tid = threadIdx.x;  // lane id (wave64)
    const long long blk_base = (long long)blockIdx.x * SLICE;
    const long long lim4 = (long long)n_items * NE - 4;
    const long long lim2 = (long long)n_items * NE - 2;

    // ---- stage both tensors: 10 x float4 + 1 x float2 each, coalesced ----
#pragma unroll
    for (int k = 0; k < 10; ++k) {
        int idx = (k * TPB + tid) * 4;
        long long g = blk_base + idx;
        g = g > lim4 ? lim4 : g;  // never hit: 262144*42 % 2688 == 0
        *(float4*)(sp + idx) = *(const float4*)(pred + g);
    }
    {
        int idx = 10 * TPB * 4 + tid * 2;  // 2560 .. 2686
        long long g = blk_base + idx;
        g = g > lim2 ? lim2 : g;
        *(float2*)(sp + idx) = *(const float2*)(pred + g);
    }
#pragma unroll
    for (int k = 0; k < 10; ++k) {
        int idx = (k * TPB + tid) * 4;
        long long g = blk_base + idx;
        g = g > lim4 ? lim4 : g;
        *(float4*)(sg + idx) = *(const float4*)(gt + g);
    }
    {
        int idx = 10 * TPB * 4 + tid * 2;
        long long g = blk_base + idx;
        g = g > lim2 ? lim2 : g;
        *(float2*)(sg + idx) = *(const float2*)(gt + g);
    }

    // ---- transposed readback (wave-synchronous, no barrier) ----
    // lane reads item `tid`: dword addr tid*42+e -> bank (10*tid+e)%32:
    // 2 lanes/bank per 32-lane phase = free (m136).
    float pd[NE], gd[NE];
#pragma unroll
    for (int e = 0; e < NE; e += 2) {
        float2 v = *(const float2*)(sp + tid * NE + e);
        pd[e] = v.x; pd[e + 1] = v.y;
        float2 w = *(const float2*)(sg + tid * NE + e);
        gd[e] = w.x; gd[e + 1] = w.y;
    }

    const int me = blockIdx.x * TPB + tid;

    // ---- moments ----
    float Sp0 = 0.f, Sp1 = 0.f, Sp2 = 0.f;
    float Sg0 = 0.f, Sg1 = 0.f, Sg2 = 0.f;
    float pp = 0.f;
    float M[3][3] = {{0.f, 0.f, 0.f}, {0.f, 0.f, 0.f}, {0.f, 0.f, 0.f}};
#pragma unroll
    for (int j = 0; j < NJ; ++j) {
        float px = pd[3 * j + 0], py = pd[3 * j + 1], pz = pd[3 * j + 2];
        float gx = gd[3 * j + 0], gy = gd[3 * j + 1], gz = gd[3 * j + 2];
        Sp0 += px; Sp1 += py; Sp2 += pz;
        Sg0 += gx; Sg1 += gy; Sg2 += gz;
        pp += px * px + py * py + pz * pz;
        M[0][0] += px * gx; M[0][1] += px * gy; M[0][2] += px * gz;
        M[1][0] += py * gx; M[1][1] += py * gy; M[1][2] += py * gz;
        M[2][0] += pz * gx; M[2][1] += pz * gy; M[2][2] += pz * gz;
    }
    const float invJ = 1.0f / (float)NJ;
    float mp[3] = {Sp0 * invJ, Sp1 * invJ, Sp2 * invJ};
    float mg[3] = {Sg0 * invJ, Sg1 * invJ, Sg2 * invJ};

    float K[3][3];
#pragma unroll
    for (int i = 0; i < 3; ++i)
#pragma unroll
        for (int j = 0; j < 3; ++j)
            K[i][j] = M[i][j] - (float)NJ * mp[i] * mg[j];
    float var1 = pp - (float)NJ * (mp[0] * mp[0] + mp[1] * mp[1] + mp[2] * mp[2]);
    var1 = fmaxf(var1, 1e-30f);

    // ---- A = K^T K, Jacobi (5 sweeps, branchless) ----
    float A[3][3];
#pragma unroll
    for (int i = 0; i < 3; ++i)
#pragma unroll
        for (int j = 0; j < 3; ++j)
            A[i][j] = K[0][i] * K[0][j] + K[1][i] * K[1][j] + K[2][i] * K[2][j];
    float V[3][3] = {{1.f, 0.f, 0.f}, {0.f, 1.f, 0.f}, {0.f, 0.f, 1.f}};
#pragma unroll
    for (int sweep = 0; sweep < 5; ++sweep) {
        jrot<0, 1, 2>(A, V);
        jrot<0, 2, 1>(A, V);
        jrot<1, 2, 0>(A, V);
    }
    float lam0 = A[0][0], lam1 = A[1][1], lam2 = A[2][2];

#define SWAPCOL(la, lb, a, b)                                     \
    {                                                             \
        float _t;                                                 \
        _t = la; la = lb; lb = _t;                                \
        _t = V[0][a]; V[0][a] = V[0][b]; V[0][b] = _t;            \
        _t = V[1][a]; V[1][a] = V[1][b]; V[1][b] = _t;            \
        _t = V[2][a]; V[2][a] = V[2][b]; V[2][b] = _t;            \
    }
    if (lam0 < lam1) SWAPCOL(lam0, lam1, 0, 1)
    if (lam0 < lam2) SWAPCOL(lam0, lam2, 0, 2)
    if (lam1 < lam2) SWAPCOL(lam1, lam2, 1, 2)
#undef SWAPCOL

    float v0[3] = {V[0][0], V[1][0], V[2][0]};
    float v1[3] = {V[0][1], V[1][1], V[2][1]};
    float v2[3] = {V[0][2], V[1][2], V[2][2]};

    // det(V) = +1
    float cxx = v0[1] * v1[2] - v0[2] * v1[1];
    float cxy = v0[2] * v1[0] - v0[0] * v1[2];
    float cxz = v0[0] * v1[1] - v0[1] * v1[0];
    float detv = cxx * v2[0] + cxy * v2[1] + cxz * v2[2];
    if (detv < 0.f) { v2[0] = -v2[0]; v2[1] = -v2[1]; v2[2] = -v2[2]; }

    // U via K*v + Gram-Schmidt; u3 = u1 x u2 -> det(U)=+1
    float w0[3], w1[3];
#pragma unroll
    for (int i = 0; i < 3; ++i) {
        w0[i] = K[i][0] * v0[0] + K[i][1] * v0[1] + K[i][2] * v0[2];
        w1[i] = K[i][0] * v1[0] + K[i][1] * v1[1] + K[i][2] * v1[2];
    }
    float inv0 = frsq(fmaxf(w0[0] * w0[0] + w0[1] * w0[1] + w0[2] * w0[2], 1e-30f));
    float u1[3] = {w0[0] * inv0, w0[1] * inv0, w0[2] * inv0};
    float d1 = u1[0] * w1[0] + u1[1] * w1[1] + u1[2] * w1[2];
    w1[0] -= d1 * u1[0]; w1[1] -= d1 * u1[1]; w1[2] -= d1 * u1[2];
    float inv1 = frsq(fmaxf(w1[0] * w1[0] + w1[1] * w1[1] + w1[2] * w1[2], 1e-30f));
    float u2[3] = {w1[0] * inv1, w1[1] * inv1, w1[2] * inv1};
    float u3[3] = {u1[1] * u2[2] - u1[2] * u2[1],
                   u1[2] * u2[0] - u1[0] * u2[2],
                   u1[0] * u2[1] - u1[1] * u2[0]};

    // R = V U^T
    float R[3][3];
#pragma unroll
    for (int i = 0; i < 3; ++i) {
        R[i][0] = v0[i] * u1[0] + v1[i] * u2[0] + v2[i] * u3[0];
        R[i][1] = v0[i] * u1[1] + v1[i] * u2[1] + v2[i] * u3[1];
        R[i][2] = v0[i] * u1[2] + v1[i] * u2[2] + v2[i] * u3[2];
    }
    float trRK = 0.f;
#pragma unroll
    for (int i = 0; i < 3; ++i)
#pragma unroll
        for (int j = 0; j < 3; ++j)
            trRK += R[i][j] * K[j][i];
    float scale = trRK * frcp(var1);

    // ---- loss from registers ----
    float acc = 0.f;
#pragma unroll
    for (int j = 0; j < NJ; ++j) {
        float x0 = pd[3 * j + 0] - mp[0];
        float x1 = pd[3 * j + 1] - mp[1];
        float x2 = pd[3 * j + 2] - mp[2];
        float y0 = gd[3 * j + 0] - mg[0];
        float y1 = gd[3 * j + 1] - mg[1];
        float y2 = gd[3 * j + 2] - mg[2];
        float e0 = scale * (R[0][0] * x0 + R[0][1] * x1 + R[0][2] * x2) - y0;
        float e1 = scale * (R[1][0] * x0 + R[1][1] * x1 + R[1][2] * x2) - y1;
        float e2 = scale * (R[2][0] * x0 + R[2][1] * x1 + R[2][2] * x2) - y2;
        acc += fsqr(e0 * e0 + e1 * e1 + e2 * e2);
    }
    if (me < n_items) out[me] = acc * invJ;
}

extern "C" void kernel_launch(void* const* d_in, const int* in_sizes, int n_in,
                              void* d_out, int out_size, void* d_ws, size_t ws_size,
                              hipStream_t stream) {
    const float* pred = (const float*)d_in[0];
    const float* gt = (const float*)d_in[1];
    float* out = (float*)d_out;
    int n_items = in_sizes[0] / NE;  // 262144
    int grid = (n_items + TPB - 1) / TPB;
    pampjpe_kernel<<<grid, TPB, 0, stream>>>(pred, gt, out, n_items);
}